// Round 7
// baseline (1080.228 us; speedup 1.0000x reference)
//
#include <hip/hip_runtime.h>
#include <hip/hip_bf16.h>

// Problem constants
#define B_ 32
#define T_ 64
#define E_ 512
#define H_ 512
#define V_ 10000
#define G4 2048   // 4*H

using bf16x8 = __attribute__((ext_vector_type(8))) short;  // 8 bf16 in 4 VGPRs
using f32x4  = __attribute__((ext_vector_type(4))) float;

__device__ inline f32x4 mfma16(bf16x8 a, bf16x8 b, f32x4 c) {
  return __builtin_amdgcn_mfma_f32_16x16x32_bf16(a, b, c, 0, 0, 0);
}

// fp32 -> bf16 round-to-nearest-even, stored as short
__device__ inline short f2bf(float x) {
  unsigned u = __builtin_bit_cast(unsigned, x);
  u = (u + 0x7fffu + ((u >> 16) & 1u)) >> 16;
  return (short)u;
}

// fast transcendental pointwise (bf16-output accuracy is the bar)
__device__ inline float fsigm(float x) {
  return __builtin_amdgcn_rcpf(1.f + __builtin_amdgcn_exp2f(-1.442695040888963f * x));
}
__device__ inline float ftanh(float x) {
  return 1.f - 2.f * __builtin_amdgcn_rcpf(1.f + __builtin_amdgcn_exp2f(2.885390081777927f * x));
}

// Swizzled 16B LDS read: row stride 1024B, byte ^= (row&7)<<4 kills the
// 16-way bank conflict of the row-major [*][512] bf16 layout (guide G4).
__device__ inline bf16x8 lds_ld16B(const short* base, int row, int col) {
  int byte = (row << 10) + (col << 1);
  byte ^= (row & 7) << 4;
  return *(const bf16x8*)((const char*)base + byte);
}

// ---------------- prep kernels ----------------

__global__ void cast_bf16_kernel(const float* __restrict__ in, short* __restrict__ out, int n) {
  int i = blockIdx.x * blockDim.x + threadIdx.x;
  int stride = gridDim.x * blockDim.x;
  for (; i < n; i += stride) out[i] = f2bf(in[i]);
}

__global__ void bsum_kernel(const float* __restrict__ bi, const float* __restrict__ bh,
                            float* __restrict__ bs) {
  int i = blockIdx.x * blockDim.x + threadIdx.x;
  if (i < G4) bs[i] = bi[i] + bh[i];
}

// xs[t][b][e] bf16 : t==0 -> features[b][e] ; t>=1 -> embed[captions[b][t-1]][e]
__global__ void build_xs_kernel(const float* __restrict__ features, const int* __restrict__ captions,
                                const float* __restrict__ embed, short* __restrict__ xs) {
  int i = blockIdx.x * blockDim.x + threadIdx.x;
  int stride = gridDim.x * blockDim.x;
  const int n = T_ * B_ * E_;
  for (; i < n; i += stride) {
    int t = i / (B_ * E_);
    int r = i - t * (B_ * E_);
    int b = r >> 9;       // /E_
    int e = r & 511;      // %E_
    float v;
    if (t == 0) v = features[b * E_ + e];
    else        v = embed[captions[b * T_ + (t - 1)] * E_ + e];
    xs[i] = f2bf(v);
  }
}

// ---------------- Gx GEMM ----------------
// Computes xs @ W_ih^T + (b_ih+b_hh), M=2048 (t*32+b), N=2048 (g*512+hc), K=512.
// OUTPUT LAYOUT: Gxt[t][g][b][hc] = [((t*4+g)*32+b)*512 + hc].

__global__ __launch_bounds__(256) void gemm_gx_kernel(const short* __restrict__ A,
                                                      const short* __restrict__ W,
                                                      const float* __restrict__ bias,
                                                      float* __restrict__ C) {
  const int lane = threadIdx.x & 63;
  const int wv   = threadIdx.x >> 6;
  const int m0 = blockIdx.y * 64 + (wv >> 1) * 32;
  const int n0 = blockIdx.x * 64 + (wv & 1) * 32;
  const int lr = lane & 15;
  const int ko = (lane >> 4) << 3;
  f32x4 acc[2][2] = {};
  const short* Ap = A + (m0 + lr) * 512 + ko;
  const short* Wp = W + (n0 + lr) * 512 + ko;
#pragma unroll
  for (int k = 0; k < 512; k += 32) {
    bf16x8 a0 = *(const bf16x8*)(Ap + k);
    bf16x8 a1 = *(const bf16x8*)(Ap + 16 * 512 + k);
    bf16x8 b0 = *(const bf16x8*)(Wp + k);
    bf16x8 b1 = *(const bf16x8*)(Wp + 16 * 512 + k);
    acc[0][0] = mfma16(a0, b0, acc[0][0]);
    acc[0][1] = mfma16(a0, b1, acc[0][1]);
    acc[1][0] = mfma16(a1, b0, acc[1][0]);
    acc[1][1] = mfma16(a1, b1, acc[1][1]);
  }
  const int cr = (lane >> 4) * 4, cc = lane & 15;
#pragma unroll
  for (int mi = 0; mi < 2; ++mi)
#pragma unroll
    for (int ni = 0; ni < 2; ++ni)
#pragma unroll
      for (int j = 0; j < 4; ++j) {
        int row = m0 + mi * 16 + cr + j;   // t*32 + b
        int col = n0 + ni * 16 + cc;       // g*512 + hc
        int tt = row >> 5, bb = row & 31;
        int g  = col >> 9, hc = col & 511;
        C[(size_t)((tt * 4 + g) * 32 + bb) * 512 + hc] = acc[mi][ni][j] + bias[col];
      }
}

// ---------------- persistent LSTM recurrence: XCD-local fast path + safe fallback ----
// 512 blocks x 128 threads. Each block reads XCC_ID and claims a worker slot
// on its XCD (first 32 win, rest exit) -> every healthy XCD redundantly
// computes the FULL recurrence; all its sync then stays in its own L2.
// Producers double-store h (plain -> own L2; agent atomic -> L3) and
// double-raise flags (plain local; agent global). Consumers poll local flags
// with a BOUNDED spin (16 iters of sc0 loads); on expiry they fall back to
// the proven agent-scope global-flag poll. Every spin is bounded or proven:
// no reachable deadlock even if XCC_ID grouping or sc0 semantics are wrong
// (worst case = R5 behavior + small wasted fast-poll).
// Redundant writes across XCDs carry identical bytes (deterministic) ->
// benign. hs in memory is always correct via the agent-scope copy.

__global__ __launch_bounds__(128) void lstm_kernel(const short* __restrict__ Whh,
                                                   const float* __restrict__ Gx,
                                                   short* __restrict__ hs,   // [T][B][H] bf16
                                                   int* __restrict__ comm) { // see layout below
  // comm layout (ints): [0..511] flags_local[8][64], [512..575] flags_global[64],
  //                     [576..583] cnt[8]
  __shared__ short Wlds[64 * 512];    // 64 KB, swizzled
  __shared__ int slot_sh;
  const int tid  = threadIdx.x;
  const int lane = tid & 63;
  const int wv   = tid >> 6;

  unsigned xcd;
  asm volatile("s_getreg_b32 %0, hwreg(HW_REG_XCC_ID)" : "=s"(xcd));
  xcd &= 7;
  if (tid == 0)
    slot_sh = __hip_atomic_fetch_add(&comm[576 + xcd], 1, __ATOMIC_RELAXED,
                                     __HIP_MEMORY_SCOPE_AGENT);
  __syncthreads();
  const int slot = slot_sh;
  if (slot >= 32) return;          // not a worker on this XCD
  const int hc0 = slot * 16;       // this block's h columns

  int* const lflags = comm + xcd * 64;   // this XCD's local flags
  int* const gflags = comm + 512;        // global flags

  // stage W_hh slice (swizzled): logical row gc = g*16+c  <-  Whh row g*512+hc0+c
  for (int i = tid * 8; i < 64 * 512; i += 128 * 8) {
    int gc = i >> 9;
    int k  = i & 511;
    int g  = gc >> 4, c = gc & 15;
    bf16x8 v = *(const bf16x8*)&Whh[(g * 512 + hc0 + c) * 512 + k];
    int byte = (i * 2) ^ ((gc & 7) << 4);
    *(bf16x8*)((char*)Wlds + byte) = v;
  }
  __syncthreads();   // one-time; no syncs inside the T-loop

  const int lr   = lane & 15;
  const int ko   = (lane >> 4) << 3;   // k-offset within 32-chunk
  const int cr   = (lane >> 4) << 2;   // hcol-rel base (0,4,8,12)
  const int cc   = lane & 15;
  const int bat  = wv * 16 + cc;       // batch of this lane's output cells
  const int brow = wv * 16 + lr;       // batch row this lane loads for B-frag

  // Gxt[t][g][bat][hc0+cr ..+4): coalesced float4 per gate
  const float* gbase = Gx + (size_t)bat * 512 + hc0 + cr;
  float4 gx0 = *(const float4*)(gbase + 0 * 32 * 512);
  float4 gx1 = *(const float4*)(gbase + 1 * 32 * 512);
  float4 gx2 = *(const float4*)(gbase + 2 * 32 * 512);
  float4 gx3 = *(const float4*)(gbase + 3 * 32 * 512);

  float cst[4] = {0.f, 0.f, 0.f, 0.f};   // cell state, static-indexed only

  for (int t = 0; t < T_; ++t) {
    f32x4 a0 = {}, a1 = {}, a2 = {}, a3 = {};   // acc per gate (i,f,g,o)
    if (t > 0) {
      // ---- fast path: bounded poll of XCD-local flags (sc0 = L1-bypass) ----
      const int* lp = lflags + lane;
      bool done = false;
      for (int it = 0; it < 16; ++it) {
        int fl;
        asm volatile("global_load_dword %0, %1, off sc0\n\t"
                     "s_waitcnt vmcnt(0)"
                     : "=v"(fl) : "v"(lp) : "memory");
        if (__all(fl >= t)) { done = true; break; }
      }
      if (!done) {
        // ---- guaranteed fallback: agent-scope global flags (proven R5 path) ----
        const int* gp = gflags + lane;
        for (;;) {
          int fl = __hip_atomic_load(gp, __ATOMIC_RELAXED, __HIP_MEMORY_SCOPE_AGENT);
          if (__all(fl >= t)) break;
          __builtin_amdgcn_s_sleep(1);
        }
      }
      asm volatile("" ::: "memory");   // no hoisting of h loads above the poll
      // h[t-1] @ W_hh^T : plain coalesced loads.
      // Fast path: hits own-L2 dirty lines (this XCD's producers wrote them).
      // Fallback: L3 read-through (agent copy preceded the global flag).
      const short* Ap = hs + (size_t)(t - 1) * (B_ * H_) + brow * 512 + ko;
#pragma unroll
      for (int kk = 0; kk < 512; kk += 32) {
        bf16x8 hb = *(const bf16x8*)(Ap + kk);
        bf16x8 w0 = lds_ld16B(Wlds,      lr, kk + ko);
        bf16x8 w1 = lds_ld16B(Wlds, 16 + lr, kk + ko);
        bf16x8 w2 = lds_ld16B(Wlds, 32 + lr, kk + ko);
        bf16x8 w3 = lds_ld16B(Wlds, 48 + lr, kk + ko);
        a0 = mfma16(w0, hb, a0);
        a1 = mfma16(w1, hb, a1);
        a2 = mfma16(w2, hb, a2);
        a3 = mfma16(w3, hb, a3);
      }
    }
    // pointwise LSTM cell, fully in-register (cols hc0+cr..+3, batch bat)
    unsigned long long hpack = 0;
#pragma unroll
    for (int j = 0; j < 4; ++j) {
      float iv = fsigm(a0[j] + ((const float*)&gx0)[j]);
      float fv = fsigm(a1[j] + ((const float*)&gx1)[j]);
      float gv = ftanh(a2[j] + ((const float*)&gx2)[j]);
      float ov = fsigm(a3[j] + ((const float*)&gx3)[j]);
      float cv = fv * cst[j] + iv * gv;
      cst[j] = cv;
      float hv = ov * ftanh(cv);
      hpack |= (unsigned long long)(unsigned short)f2bf(hv) << (16 * j);
    }
    // double h store: plain (own L2, local visibility) + agent atomic (L3)
    unsigned long long* hp =
        (unsigned long long*)(hs + (size_t)t * (B_ * H_) + bat * 512 + hc0 + cr);
    *hp = hpack;
    __hip_atomic_store(hp, hpack, __ATOMIC_RELAXED, __HIP_MEMORY_SCOPE_AGENT);
    if (t < T_ - 1) {
      // drain both h copies, then double-raise this wave's flag
      asm volatile("s_waitcnt vmcnt(0)" ::: "memory");
      if (lane == 0) {
        int  fv  = t + 1;
        int* lfp = lflags + (slot * 2 + wv);
        asm volatile("global_store_dword %0, %1, off" :: "v"(lfp), "v"(fv) : "memory");
        __hip_atomic_store(gflags + (slot * 2 + wv), fv, __ATOMIC_RELAXED,
                           __HIP_MEMORY_SCOPE_AGENT);
      }
      // prefetch Gx for t+1 (completes under the next poll)
      const float* g0 = gbase + (size_t)(t + 1) * 128 * 512;
      gx0 = *(const float4*)(g0 + 0 * 32 * 512);
      gx1 = *(const float4*)(g0 + 1 * 32 * 512);
      gx2 = *(const float4*)(g0 + 2 * 32 * 512);
      gx3 = *(const float4*)(g0 + 3 * 32 * 512);
    }
  }
}

// ---------------- FC GEMM: out[b][t][v] = hs @ fc_W^T + fc_b ----------------
// M=2048 (rows t*32+b), N=10000, K=512.

__global__ __launch_bounds__(256) void gemm_fc_kernel(const short* __restrict__ A,
                                                      const short* __restrict__ W,
                                                      const float* __restrict__ bias,
                                                      float* __restrict__ out) {
  const int lane = threadIdx.x & 63;
  const int wv   = threadIdx.x >> 6;
  const int m0 = blockIdx.y * 64 + (wv >> 1) * 32;
  const int n0 = blockIdx.x * 64 + (wv & 1) * 32;
  const int lr = lane & 15;
  const int ko = (lane >> 4) << 3;
  const int nr0 = n0 + lr, nr1 = n0 + 16 + lr;
  const bool v0 = nr0 < V_, v1 = nr1 < V_;
  f32x4 acc[2][2] = {};
  const short* Ap  = A + (m0 + lr) * 512 + ko;
  const short* Wp0 = W + nr0 * 512 + ko;
  const short* Wp1 = W + nr1 * 512 + ko;
  const bf16x8 zb = {};
#pragma unroll
  for (int k = 0; k < 512; k += 32) {
    bf16x8 a0 = *(const bf16x8*)(Ap + k);
    bf16x8 a1 = *(const bf16x8*)(Ap + 16 * 512 + k);
    bf16x8 b0 = v0 ? *(const bf16x8*)(Wp0 + k) : zb;
    bf16x8 b1 = v1 ? *(const bf16x8*)(Wp1 + k) : zb;
    acc[0][0] = mfma16(a0, b0, acc[0][0]);
    acc[0][1] = mfma16(a0, b1, acc[0][1]);
    acc[1][0] = mfma16(a1, b0, acc[1][0]);
    acc[1][1] = mfma16(a1, b1, acc[1][1]);
  }
  const int cr = (lane >> 4) * 4, cc = lane & 15;
#pragma unroll
  for (int mi = 0; mi < 2; ++mi)
#pragma unroll
    for (int ni = 0; ni < 2; ++ni)
#pragma unroll
      for (int j = 0; j < 4; ++j) {
        int row = m0 + mi * 16 + cr + j;
        int col = n0 + ni * 16 + cc;
        if (col < V_) {
          // row = t*32 + b  ->  out[b][t][col]
          out[(row & 31) * (T_ * V_) + (row >> 5) * V_ + col] = acc[mi][ni][j] + bias[col];
        }
      }
}

// ---------------- launch ----------------

extern "C" void kernel_launch(void* const* d_in, const int* in_sizes, int n_in,
                              void* d_out, int out_size, void* d_ws, size_t ws_size,
                              hipStream_t stream) {
  const float* features = (const float*)d_in[0];
  const int*   captions = (const int*)d_in[1];
  const float* embed    = (const float*)d_in[3];
  const float* W_ih     = (const float*)d_in[4];
  const float* W_hh     = (const float*)d_in[5];
  const float* b_ih     = (const float*)d_in[6];
  const float* b_hh     = (const float*)d_in[7];
  const float* fc_W     = (const float*)d_in[8];
  const float* fc_b     = (const float*)d_in[9];
  float* out = (float*)d_out;

  char* ws = (char*)d_ws;
  size_t off = 0;
  auto alloc = [&](size_t bytes) -> void* {
    off = (off + 255) & ~(size_t)255;
    void* p = ws + off;
    off += bytes;
    return p;
  };
  int*      comm   = (int*)     alloc(4096);  // flags_local + flags_global + cnt
  short*    wih_bf = (short*)   alloc((size_t)G4 * E_ * 2);
  short*    whh_bf = (short*)   alloc((size_t)G4 * H_ * 2);
  short*    fcw_bf = (short*)   alloc((size_t)V_ * H_ * 2);
  float*    bsum   = (float*)   alloc((size_t)G4 * 4);
  float*    Gx     = (float*)   alloc((size_t)T_ * B_ * G4 * 4);
  short*    xs     = (short*)   alloc((size_t)T_ * B_ * E_ * 2);
  short*    hs     = (short*)   alloc((size_t)T_ * B_ * H_ * 2);

  hipMemsetAsync(comm, 0, 4096, stream);
  cast_bf16_kernel<<<1024, 256, 0, stream>>>(W_ih, wih_bf, G4 * E_);
  cast_bf16_kernel<<<1024, 256, 0, stream>>>(W_hh, whh_bf, G4 * H_);
  cast_bf16_kernel<<<2048, 256, 0, stream>>>(fc_W, fcw_bf, V_ * H_);
  bsum_kernel<<<8, 256, 0, stream>>>(b_ih, b_hh, bsum);
  build_xs_kernel<<<1024, 256, 0, stream>>>(features, captions, embed, xs);
  gemm_gx_kernel<<<dim3(32, 32), 256, 0, stream>>>(xs, wih_bf, bsum, Gx);
  lstm_kernel<<<512, 128, 0, stream>>>(whh_bf, Gx, hs, comm);
  gemm_fc_kernel<<<dim3(157, 32), 256, 0, stream>>>(hs, fcw_bf, fc_b, out);
}

// Round 8
// 361.561 us; speedup vs baseline: 2.9877x; 2.9877x over previous
//
#include <hip/hip_runtime.h>
#include <hip/hip_bf16.h>

// Problem constants
#define B_ 32
#define T_ 64
#define E_ 512
#define H_ 512
#define V_ 10000
#define G4 2048   // 4*H

using bf16x8 = __attribute__((ext_vector_type(8))) short;  // 8 bf16 in 4 VGPRs
using f32x4  = __attribute__((ext_vector_type(4))) float;

__device__ inline f32x4 mfma16(bf16x8 a, bf16x8 b, f32x4 c) {
  return __builtin_amdgcn_mfma_f32_16x16x32_bf16(a, b, c, 0, 0, 0);
}

// fp32 -> bf16 round-to-nearest-even, stored as short
__device__ inline short f2bf(float x) {
  unsigned u = __builtin_bit_cast(unsigned, x);
  u = (u + 0x7fffu + ((u >> 16) & 1u)) >> 16;
  return (short)u;
}

// fast transcendental pointwise (bf16-output accuracy is the bar)
__device__ inline float fsigm(float x) {
  return __builtin_amdgcn_rcpf(1.f + __builtin_amdgcn_exp2f(-1.442695040888963f * x));
}
__device__ inline float ftanh(float x) {
  return 1.f - 2.f * __builtin_amdgcn_rcpf(1.f + __builtin_amdgcn_exp2f(2.885390081777927f * x));
}

// Swizzled 16B LDS read: row stride 1024B, byte ^= (row&7)<<4 kills the
// 16-way bank conflict of the row-major [*][512] bf16 layout (guide G4).
__device__ inline bf16x8 lds_ld16B(const short* base, int row, int col) {
  int byte = (row << 10) + (col << 1);
  byte ^= (row & 7) << 4;
  return *(const bf16x8*)((const char*)base + byte);
}

// ---------------- fused prep kernel ----------------
// One grid-stride kernel: cast W_ih, W_hh, fc_W to bf16; bsum; build xs.

#define N1 (G4 * E_)          // W_ih
#define N2 (N1 + G4 * H_)     // W_hh
#define N3 (N2 + V_ * H_)     // fc_W
#define N4 (N3 + G4)          // bsum
#define N5 (N4 + T_ * B_ * E_)// xs

__global__ void prep_kernel(const float* __restrict__ W_ih, const float* __restrict__ W_hh,
                            const float* __restrict__ fc_W, const float* __restrict__ b_ih,
                            const float* __restrict__ b_hh, const float* __restrict__ features,
                            const int* __restrict__ captions, const float* __restrict__ embed,
                            short* __restrict__ wih_bf, short* __restrict__ whh_bf,
                            short* __restrict__ fcw_bf, float* __restrict__ bsum,
                            short* __restrict__ xs) {
  int i = blockIdx.x * blockDim.x + threadIdx.x;
  int stride = gridDim.x * blockDim.x;
  for (; i < N5; i += stride) {
    if (i < N1) {
      wih_bf[i] = f2bf(W_ih[i]);
    } else if (i < N2) {
      int j = i - N1;
      whh_bf[j] = f2bf(W_hh[j]);
    } else if (i < N3) {
      int j = i - N2;
      fcw_bf[j] = f2bf(fc_W[j]);
    } else if (i < N4) {
      int j = i - N3;
      bsum[j] = b_ih[j] + b_hh[j];
    } else {
      int j = i - N4;                 // [t][b][e]
      int t = j / (B_ * E_);
      int r = j - t * (B_ * E_);
      int b = r >> 9;
      int e = r & 511;
      float v;
      if (t == 0) v = features[b * E_ + e];
      else        v = embed[captions[b * T_ + (t - 1)] * E_ + e];
      xs[j] = f2bf(v);
    }
  }
}

// ---------------- Gx GEMM ----------------
// Computes xs @ W_ih^T + (b_ih+b_hh), M=2048 (t*32+b), N=2048 (g*512+hc), K=512.
// OUTPUT LAYOUT: Gxt[t][g][b][hc] = [((t*4+g)*32+b)*512 + hc].

__global__ __launch_bounds__(256) void gemm_gx_kernel(const short* __restrict__ A,
                                                      const short* __restrict__ W,
                                                      const float* __restrict__ bias,
                                                      float* __restrict__ C) {
  const int lane = threadIdx.x & 63;
  const int wv   = threadIdx.x >> 6;
  const int m0 = blockIdx.y * 64 + (wv >> 1) * 32;
  const int n0 = blockIdx.x * 64 + (wv & 1) * 32;
  const int lr = lane & 15;
  const int ko = (lane >> 4) << 3;
  f32x4 acc[2][2] = {};
  const short* Ap = A + (m0 + lr) * 512 + ko;
  const short* Wp = W + (n0 + lr) * 512 + ko;
#pragma unroll
  for (int k = 0; k < 512; k += 32) {
    bf16x8 a0 = *(const bf16x8*)(Ap + k);
    bf16x8 a1 = *(const bf16x8*)(Ap + 16 * 512 + k);
    bf16x8 b0 = *(const bf16x8*)(Wp + k);
    bf16x8 b1 = *(const bf16x8*)(Wp + 16 * 512 + k);
    acc[0][0] = mfma16(a0, b0, acc[0][0]);
    acc[0][1] = mfma16(a0, b1, acc[0][1]);
    acc[1][0] = mfma16(a1, b0, acc[1][0]);
    acc[1][1] = mfma16(a1, b1, acc[1][1]);
  }
  const int cr = (lane >> 4) * 4, cc = lane & 15;
#pragma unroll
  for (int mi = 0; mi < 2; ++mi)
#pragma unroll
    for (int ni = 0; ni < 2; ++ni)
#pragma unroll
      for (int j = 0; j < 4; ++j) {
        int row = m0 + mi * 16 + cr + j;   // t*32 + b
        int col = n0 + ni * 16 + cc;       // g*512 + hc
        int tt = row >> 5, bb = row & 31;
        int g  = col >> 9, hc = col & 511;
        C[(size_t)((tt * 4 + g) * 32 + bb) * 512 + hc] = acc[mi][ni][j] + bias[col];
      }
}

// ---------------- persistent LSTM recurrence, batch-group split ----------------
// The LSTM recurrence is INDEPENDENT per batch sample; only the K-dim (h
// columns) couples blocks. Split batch 32 -> 2 groups of 16. 64 blocks x 64
// threads (1 wave): block = (bg, slot) owns batch group bg (16 samples) and
// h columns [slot*16, slot*16+16). Each group of 32 waves syncs ONLY among
// itself: 32 flags, 16KB h exchange (16 rows x 512 cols) per step.
// Protocol identical to the verified R5 one: agent-scope h store (-> L3),
// vmcnt(0) drain, agent-scope flag store, relaxed agent poll, plain
// coalesced h loads (every hs address is written before any read within
// this dispatch; dispatch-start acquire kills stale L2 lines).

__global__ __launch_bounds__(64) void lstm_kernel(const short* __restrict__ Whh,
                                                  const float* __restrict__ Gx,
                                                  short* __restrict__ hs,   // [T][B][H] bf16
                                                  int* __restrict__ flags) { // [2][32]
  __shared__ short Wlds[64 * 512];    // 64 KB, swizzled
  const int lane = threadIdx.x;       // 0..63
  const int blk  = blockIdx.x;        // 0..63
  const int bg   = blk >> 5;          // batch group 0/1
  const int slot = blk & 31;          // h-column slot
  const int hc0  = slot * 16;
  int* const gflags = flags + bg * 32;

  // stage W_hh slice (swizzled): logical row gc = g*16+c  <-  Whh row g*512+hc0+c
  for (int i = lane * 8; i < 64 * 512; i += 64 * 8) {
    int gc = i >> 9;
    int k  = i & 511;
    int g  = gc >> 4, c = gc & 15;
    bf16x8 v = *(const bf16x8*)&Whh[(g * 512 + hc0 + c) * 512 + k];
    int byte = (i * 2) ^ ((gc & 7) << 4);
    *(bf16x8*)((char*)Wlds + byte) = v;
  }
  __syncthreads();

  const int lr  = lane & 15;
  const int ko  = (lane >> 4) << 3;   // k-offset within 32-chunk
  const int cr  = (lane >> 4) << 2;   // hcol-rel base (0,4,8,12)
  const int cc  = lane & 15;
  const int bat = bg * 16 + cc;       // global batch of this lane's cells
  const int hrow = bg * 16 + lr;      // h row this lane loads for B-frag

  // Gxt[t][g][bat][hc0+cr ..+4): one float4 per gate
  const float* gbase = Gx + (size_t)bat * 512 + hc0 + cr;
  float4 gx0 = *(const float4*)(gbase + 0 * 32 * 512);
  float4 gx1 = *(const float4*)(gbase + 1 * 32 * 512);
  float4 gx2 = *(const float4*)(gbase + 2 * 32 * 512);
  float4 gx3 = *(const float4*)(gbase + 3 * 32 * 512);

  float cst[4] = {0.f, 0.f, 0.f, 0.f};   // cell state, static-indexed only

  for (int t = 0; t < T_; ++t) {
    f32x4 a0 = {}, a1 = {}, a2 = {}, a3 = {};   // acc per gate (i,f,g,o)
    if (t > 0) {
      // wait for this GROUP's 32 producer blocks to finish step t-1
      const int* fp = gflags + (lane & 31);
      for (;;) {
        int fl = __hip_atomic_load(fp, __ATOMIC_RELAXED, __HIP_MEMORY_SCOPE_AGENT);
        if (__all(fl >= t)) break;
      }
      asm volatile("" ::: "memory");   // no hoisting of h loads above the poll
      // h[t-1][group rows] @ W_hh^T : plain coalesced loads (16KB for group)
      const short* Ap = hs + (size_t)(t - 1) * (B_ * H_) + hrow * 512 + ko;
#pragma unroll
      for (int kk = 0; kk < 512; kk += 32) {
        bf16x8 hb = *(const bf16x8*)(Ap + kk);
        bf16x8 w0 = lds_ld16B(Wlds,      lr, kk + ko);
        bf16x8 w1 = lds_ld16B(Wlds, 16 + lr, kk + ko);
        bf16x8 w2 = lds_ld16B(Wlds, 32 + lr, kk + ko);
        bf16x8 w3 = lds_ld16B(Wlds, 48 + lr, kk + ko);
        a0 = mfma16(w0, hb, a0);
        a1 = mfma16(w1, hb, a1);
        a2 = mfma16(w2, hb, a2);
        a3 = mfma16(w3, hb, a3);
      }
    }
    // pointwise LSTM cell, fully in-register (cols hc0+cr..+3, batch bat)
    unsigned long long hpack = 0;
#pragma unroll
    for (int j = 0; j < 4; ++j) {
      float iv = fsigm(a0[j] + ((const float*)&gx0)[j]);
      float fv = fsigm(a1[j] + ((const float*)&gx1)[j]);
      float gv = ftanh(a2[j] + ((const float*)&gx2)[j]);
      float ov = fsigm(a3[j] + ((const float*)&gx3)[j]);
      float cv = fv * cst[j] + iv * gv;
      cst[j] = cv;
      float hv = ov * ftanh(cv);
      hpack |= (unsigned long long)(unsigned short)f2bf(hv) << (16 * j);
    }
    // one 8B agent-scope store: hs[t][bat][hc0+cr .. +4]  (write-through to L3)
    __hip_atomic_store(
        (unsigned long long*)(hs + (size_t)t * (B_ * H_) + bat * 512 + hc0 + cr),
        hpack, __ATOMIC_RELAXED, __HIP_MEMORY_SCOPE_AGENT);
    if (t < T_ - 1) {
      // drain own store to the coherent point, then raise this block's flag
      asm volatile("s_waitcnt vmcnt(0)" ::: "memory");
      if (lane == 0)
        __hip_atomic_store(gflags + slot, t + 1, __ATOMIC_RELAXED,
                           __HIP_MEMORY_SCOPE_AGENT);
      // prefetch Gx for t+1 (completes under the next poll)
      const float* g0 = gbase + (size_t)(t + 1) * 128 * 512;
      gx0 = *(const float4*)(g0 + 0 * 32 * 512);
      gx1 = *(const float4*)(g0 + 1 * 32 * 512);
      gx2 = *(const float4*)(g0 + 2 * 32 * 512);
      gx3 = *(const float4*)(g0 + 3 * 32 * 512);
    }
  }
}

// ---------------- FC GEMM: out[b][t][v] = hs @ fc_W^T + fc_b ----------------
// M=2048 (rows t*32+b), N=10000, K=512. 128x128 block tile, wave = 64x64
// (acc 4x4): 16 MFMA per 8 global loads per kk (2x the density of 64x64).

__global__ __launch_bounds__(256) void gemm_fc_kernel(const short* __restrict__ A,
                                                      const short* __restrict__ W,
                                                      const float* __restrict__ bias,
                                                      float* __restrict__ out) {
  const int lane = threadIdx.x & 63;
  const int wv   = threadIdx.x >> 6;
  const int m0 = blockIdx.y * 128 + (wv >> 1) * 64;
  const int n0 = blockIdx.x * 128 + (wv & 1) * 64;
  const int lr = lane & 15;
  const int ko = (lane >> 4) << 3;
  f32x4 acc[4][4] = {};
  const short* Ap = A + (m0 + lr) * 512 + ko;
  const short* Wp[4];
  bool vn[4];
#pragma unroll
  for (int ni = 0; ni < 4; ++ni) {
    int nr = n0 + ni * 16 + lr;
    vn[ni] = nr < V_;
    Wp[ni] = W + (size_t)(vn[ni] ? nr : 0) * 512 + ko;
  }
  const bf16x8 zb = {};
#pragma unroll 2
  for (int k = 0; k < 512; k += 32) {
    bf16x8 af[4], bf[4];
#pragma unroll
    for (int mi = 0; mi < 4; ++mi) af[mi] = *(const bf16x8*)(Ap + mi * 16 * 512 + k);
#pragma unroll
    for (int ni = 0; ni < 4; ++ni) bf[ni] = vn[ni] ? *(const bf16x8*)(Wp[ni] + k) : zb;
#pragma unroll
    for (int mi = 0; mi < 4; ++mi)
#pragma unroll
      for (int ni = 0; ni < 4; ++ni)
        acc[mi][ni] = mfma16(af[mi], bf[ni], acc[mi][ni]);
  }
  const int cr = (lane >> 4) * 4, cc = lane & 15;
#pragma unroll
  for (int mi = 0; mi < 4; ++mi)
#pragma unroll
    for (int ni = 0; ni < 4; ++ni)
#pragma unroll
      for (int j = 0; j < 4; ++j) {
        int row = m0 + mi * 16 + cr + j;
        int col = n0 + ni * 16 + cc;
        if (col < V_) {
          // row = t*32 + b  ->  out[b][t][col]
          out[(row & 31) * (T_ * V_) + (row >> 5) * V_ + col] = acc[mi][ni][j] + bias[col];
        }
      }
}

// ---------------- launch ----------------

extern "C" void kernel_launch(void* const* d_in, const int* in_sizes, int n_in,
                              void* d_out, int out_size, void* d_ws, size_t ws_size,
                              hipStream_t stream) {
  const float* features = (const float*)d_in[0];
  const int*   captions = (const int*)d_in[1];
  const float* embed    = (const float*)d_in[3];
  const float* W_ih     = (const float*)d_in[4];
  const float* W_hh     = (const float*)d_in[5];
  const float* b_ih     = (const float*)d_in[6];
  const float* b_hh     = (const float*)d_in[7];
  const float* fc_W     = (const float*)d_in[8];
  const float* fc_b     = (const float*)d_in[9];
  float* out = (float*)d_out;

  char* ws = (char*)d_ws;
  size_t off = 0;
  auto alloc = [&](size_t bytes) -> void* {
    off = (off + 255) & ~(size_t)255;
    void* p = ws + off;
    off += bytes;
    return p;
  };
  int*      flags  = (int*)     alloc(4096);
  short*    wih_bf = (short*)   alloc((size_t)G4 * E_ * 2);
  short*    whh_bf = (short*)   alloc((size_t)G4 * H_ * 2);
  short*    fcw_bf = (short*)   alloc((size_t)V_ * H_ * 2);
  float*    bsum   = (float*)   alloc((size_t)G4 * 4);
  float*    Gx     = (float*)   alloc((size_t)T_ * B_ * G4 * 4);
  short*    xs     = (short*)   alloc((size_t)T_ * B_ * E_ * 2);
  short*    hs     = (short*)   alloc((size_t)T_ * B_ * H_ * 2);

  hipMemsetAsync(flags, 0, 4096, stream);
  prep_kernel<<<2048, 256, 0, stream>>>(W_ih, W_hh, fc_W, b_ih, b_hh,
                                        features, captions, embed,
                                        wih_bf, whh_bf, fcw_bf, bsum, xs);
  gemm_gx_kernel<<<dim3(32, 32), 256, 0, stream>>>(xs, wih_bf, bsum, Gx);
  lstm_kernel<<<64, 64, 0, stream>>>(whh_bf, Gx, hs, flags);
  gemm_fc_kernel<<<dim3(79, 16), 256, 0, stream>>>(hs, fcw_bf, fc_b, out);
}